// Round 3
// baseline (299.505 us; speedup 1.0000x reference)
//
#include <hip/hip_runtime.h>
#include <hip/hip_bf16.h>

#define EMBED 128
#define HEADS 8
#define DH 16
#define FFN 512
#define BB 16
#define NN 256

// ---------------- Kernel A: LN1 + QKV projection (one block per row) -------
__global__ __launch_bounds__(128) void ln1_qkv_kernel(
    const float* __restrict__ x,
    const float* __restrict__ ln1_g, const float* __restrict__ ln1_b,
    const float* __restrict__ Wq, const float* __restrict__ bq,
    const float* __restrict__ Wk, const float* __restrict__ bk,
    const float* __restrict__ Wv, const float* __restrict__ bv,
    float* __restrict__ q, float* __restrict__ k, float* __restrict__ v)
{
    const int row = blockIdx.x;          // b*N + i
    const int e = threadIdx.x;           // 0..127
    __shared__ float red[128];
    __shared__ float xn[128];

    float xv = x[(size_t)row * EMBED + e];

    red[e] = xv;
    __syncthreads();
    for (int s = 64; s > 0; s >>= 1) { if (e < s) red[e] += red[e + s]; __syncthreads(); }
    float mu = red[0] * (1.0f / EMBED);
    __syncthreads();
    float d = xv - mu;
    red[e] = d * d;
    __syncthreads();
    for (int s = 64; s > 0; s >>= 1) { if (e < s) red[e] += red[e + s]; __syncthreads(); }
    float var = red[0] * (1.0f / EMBED);
    float rs = rsqrtf(var + 1e-5f);
    xn[e] = d * rs * ln1_g[e] + ln1_b[e];
    __syncthreads();

    float aq = bq[e], ak = bk[e], av = bv[e];
    #pragma unroll 8
    for (int c = 0; c < EMBED; ++c) {
        float xc = xn[c];
        aq += xc * Wq[c * EMBED + e];
        ak += xc * Wk[c * EMBED + e];
        av += xc * Wv[c * EMBED + e];
    }
    size_t o = (size_t)row * EMBED + e;
    q[o] = aq; k[o] = ak; v[o] = av;
}

// ---- Kernel B: scores (content + pos) + softmax -> probs ------------------
// One block per (b,i) row. Lane owns a full head-slice (16 dims): the hot
// loop is pure {load, FMA, one ds_write} -- no cross-lane ops, no lgkm waits.
__global__ __launch_bounds__(256) void scores_softmax_kernel(
    const float* __restrict__ pe,
    const float* __restrict__ mask,
    const float* __restrict__ q, const float* __restrict__ k,
    float* __restrict__ probs)
{
    const int row = blockIdx.x;      // b*N + i
    const int bb  = row >> 8;        // N = 256
    const int t   = threadIdx.x;     // 0..255
    const int l   = t & 63;          // lane
    const int w   = t >> 6;          // wave 0..3
    const int h   = l & 7;           // head owned by this lane
    const int j0  = 8 * w + (l >> 3);

    __shared__ float sc[HEADS][260];   // stride 260 -> <=2-way bank conflicts

    // q fragment for this lane's head (broadcast loads)
    const float* qp = q + (size_t)row * EMBED + h * DH;
    const float4 q0 = *reinterpret_cast<const float4*>(qp);
    const float4 q1 = *reinterpret_cast<const float4*>(qp + 4);
    const float4 q2 = *reinterpret_cast<const float4*>(qp + 8);
    const float4 q3 = *reinterpret_cast<const float4*>(qp + 12);

    const size_t pe_base = (size_t)row * NN * EMBED + h * DH;
    const size_t k_base  = (size_t)bb * NN * EMBED + h * DH;
    const size_t mrow    = (size_t)row * NN;

    #pragma unroll 2
    for (int r = 0; r < 8; ++r) {
        const int j = j0 + 32 * r;
        const float4* kp = reinterpret_cast<const float4*>(k  + k_base  + (size_t)j * EMBED);
        const float4* pp = reinterpret_cast<const float4*>(pe + pe_base + (size_t)j * EMBED);
        const float4 k0 = kp[0], k1 = kp[1], k2 = kp[2], k3 = kp[3];
        const float4 p0 = pp[0], p1 = pp[1], p2 = pp[2], p3 = pp[3];
        const float mk = mask[mrow + j];
        float s =
            q0.x*(k0.x+p0.x) + q0.y*(k0.y+p0.y) + q0.z*(k0.z+p0.z) + q0.w*(k0.w+p0.w)
          + q1.x*(k1.x+p1.x) + q1.y*(k1.y+p1.y) + q1.z*(k1.z+p1.z) + q1.w*(k1.w+p1.w)
          + q2.x*(k2.x+p2.x) + q2.y*(k2.y+p2.y) + q2.z*(k2.z+p2.z) + q2.w*(k2.w+p2.w)
          + q3.x*(k3.x+p3.x) + q3.y*(k3.y+p3.y) + q3.z*(k3.z+p3.z) + q3.w*(k3.w+p3.w);
        sc[h][j] = s * 0.25f + mk;     // 1/sqrt(16) = 0.25
    }
    __syncthreads();

    // softmax per head; group g (32 lanes) handles head g; write probs
    {
        const int g  = t >> 5;
        const int l5 = t & 31;
        float vals[8];
        float m = -1e30f;
        #pragma unroll
        for (int r = 0; r < 8; ++r) { vals[r] = sc[g][l5 + 32 * r]; m = fmaxf(m, vals[r]); }
        #pragma unroll
        for (int off = 16; off >= 1; off >>= 1) m = fmaxf(m, __shfl_xor(m, off));
        float ssum = 0.f;
        #pragma unroll
        for (int r = 0; r < 8; ++r) { float e2 = __expf(vals[r] - m); vals[r] = e2; ssum += e2; }
        #pragma unroll
        for (int off = 16; off >= 1; off >>= 1) ssum += __shfl_xor(ssum, off);
        float inv = 1.0f / ssum;
        float* pout = probs + ((size_t)row * HEADS + g) * NN;
        #pragma unroll
        for (int r = 0; r < 8; ++r) pout[l5 + 32 * r] = vals[r] * inv;
    }
}

// ---- Kernel C: PV + Wo + residual + LN2 + FFN + residual ------------------
// One block per 4 rows of the same batch: weights/v read once, used 4x.
__global__ __launch_bounds__(256) void pv_ffn_kernel(
    const float* __restrict__ x,
    const float* __restrict__ probs,
    const float* __restrict__ v,
    const float* __restrict__ Wo, const float* __restrict__ bo,
    const float* __restrict__ ln2_g, const float* __restrict__ ln2_b,
    const float* __restrict__ W1, const float* __restrict__ b1,
    const float* __restrict__ W2, const float* __restrict__ b2,
    float* __restrict__ out)
{
    const int blk  = blockIdx.x;         // 0..1023
    const int b    = blk >> 6;           // 64 blocks per batch
    const int row0 = b * NN + ((blk & 63) << 2);   // first of 4 global rows
    const int t    = threadIdx.x;        // 0..255

    __shared__ float pr[4][HEADS][NN + 1];   // ~32.9 KB, padded for banks
    __shared__ float pvred[2][4][EMBED];
    __shared__ float ctx[4][EMBED];
    __shared__ float x2s[4][EMBED];
    __shared__ float xn2[4][EMBED];
    __shared__ float hb[4][FFN];
    __shared__ float mus[4], rss[4];

    // stage probs for 4 rows: 32 (r,h) segments of 256 floats, coalesced
    #pragma unroll
    for (int rh = 0; rh < 32; ++rh) {
        const int r = rh >> 3, h = rh & 7;
        pr[r][h][t] = probs[((size_t)(row0 + r) * HEADS + h) * NN + t];
    }
    __syncthreads();

    // ---- PV: ctx[r][e] = sum_j pr[r][h(e)][j] * v[b,j,e] ------------------
    {
        const int e = t & 127, half = t >> 7, h = e >> 4;
        float a0 = 0.f, a1 = 0.f, a2 = 0.f, a3 = 0.f;
        const float* vb = v + ((size_t)(b * NN + half * 128)) * EMBED + e;
        const float* p0 = &pr[0][h][half * 128];
        const float* p1 = &pr[1][h][half * 128];
        const float* p2 = &pr[2][h][half * 128];
        const float* p3 = &pr[3][h][half * 128];
        #pragma unroll 8
        for (int j = 0; j < 128; ++j) {
            const float vv = vb[(size_t)j * EMBED];
            a0 += p0[j] * vv; a1 += p1[j] * vv; a2 += p2[j] * vv; a3 += p3[j] * vv;
        }
        pvred[half][0][e] = a0; pvred[half][1][e] = a1;
        pvred[half][2][e] = a2; pvred[half][3][e] = a3;
    }
    __syncthreads();
    if (t < 128) {
        #pragma unroll
        for (int r = 0; r < 4; ++r) ctx[r][t] = pvred[0][r][t] + pvred[1][r][t];
    }
    __syncthreads();

    // ---- Wo + residual: thread (e, rp) handles rows {2rp, 2rp+1} ----------
    {
        const int e = t & 127, rp = t >> 7;
        float a0 = bo[e], a1 = bo[e];
        #pragma unroll 8
        for (int c = 0; c < EMBED; ++c) {
            const float w = Wo[c * EMBED + e];
            a0 += ctx[2 * rp][c] * w;
            a1 += ctx[2 * rp + 1][c] * w;
        }
        a0 += x[(size_t)(row0 + 2 * rp) * EMBED + e];
        a1 += x[(size_t)(row0 + 2 * rp + 1) * EMBED + e];
        x2s[2 * rp][e] = a0;
        x2s[2 * rp + 1][e] = a1;
    }
    __syncthreads();

    // ---- LN2 stats: wave w (0..3) reduces row w via shuffles --------------
    {
        const int wid = t >> 6, l64 = t & 63;
        if (wid < 4) {
            const float v0 = x2s[wid][l64], v1 = x2s[wid][l64 + 64];
            float s = v0 + v1;
            float sq = v0 * v0 + v1 * v1;
            #pragma unroll
            for (int off = 32; off >= 1; off >>= 1) {
                s  += __shfl_xor(s, off);
                sq += __shfl_xor(sq, off);
            }
            if (l64 == 0) {
                const float mu = s * (1.0f / EMBED);
                const float var = sq * (1.0f / EMBED) - mu * mu;
                mus[wid] = mu;
                rss[wid] = rsqrtf(var + 1e-5f);
            }
        }
    }
    __syncthreads();
    {
        #pragma unroll
        for (int rr = 0; rr < 2; ++rr) {
            const int flat = t + 256 * rr;       // 0..511 = r*128+e
            const int r = flat >> 7, e = flat & 127;
            xn2[r][e] = (x2s[r][e] - mus[r]) * rss[r] * ln2_g[e] + ln2_b[e];
        }
    }
    __syncthreads();

    // ---- FFN layer 1: thread t covers hidden cols {t, t+256}, 4 rows ------
    {
        float h0[4], h1[4];
        #pragma unroll
        for (int r = 0; r < 4; ++r) { h0[r] = b1[t]; h1[r] = b1[t + 256]; }
        #pragma unroll 4
        for (int c = 0; c < EMBED; ++c) {
            const float w0 = W1[c * FFN + t];
            const float w1 = W1[c * FFN + t + 256];
            #pragma unroll
            for (int r = 0; r < 4; ++r) {
                const float xc = xn2[r][c];
                h0[r] += xc * w0;
                h1[r] += xc * w1;
            }
        }
        #pragma unroll
        for (int r = 0; r < 4; ++r) {
            hb[r][t]       = fmaxf(h0[r], 0.f);
            hb[r][t + 256] = fmaxf(h1[r], 0.f);
        }
    }
    __syncthreads();

    // ---- FFN layer 2 + residual: thread (e, rp) rows {2rp, 2rp+1} ---------
    {
        const int e = t & 127, rp = t >> 7;
        const int ra = 2 * rp, rb = 2 * rp + 1;
        float a0 = b2[e], a1 = b2[e];
        #pragma unroll 8
        for (int f = 0; f < FFN; ++f) {
            const float w = W2[f * EMBED + e];
            a0 += hb[ra][f] * w;
            a1 += hb[rb][f] * w;
        }
        out[(size_t)(row0 + ra) * EMBED + e] = x2s[ra][e] + a0;
        out[(size_t)(row0 + rb) * EMBED + e] = x2s[rb][e] + a1;
    }
}

extern "C" void kernel_launch(void* const* d_in, const int* in_sizes, int n_in,
                              void* d_out, int out_size, void* d_ws, size_t ws_size,
                              hipStream_t stream) {
    const float* x    = (const float*)d_in[0];
    const float* pe   = (const float*)d_in[1];
    const float* mask = (const float*)d_in[2];
    const float* ln1g = (const float*)d_in[3];
    const float* ln1b = (const float*)d_in[4];
    const float* Wq   = (const float*)d_in[5];
    const float* bq   = (const float*)d_in[6];
    const float* Wk   = (const float*)d_in[7];
    const float* bk   = (const float*)d_in[8];
    const float* Wv   = (const float*)d_in[9];
    const float* bv   = (const float*)d_in[10];
    const float* Wo   = (const float*)d_in[11];
    const float* bo   = (const float*)d_in[12];
    const float* ln2g = (const float*)d_in[13];
    const float* ln2b = (const float*)d_in[14];
    const float* W1   = (const float*)d_in[15];
    const float* b1   = (const float*)d_in[16];
    const float* W2   = (const float*)d_in[17];
    const float* b2   = (const float*)d_in[18];
    float* out = (float*)d_out;

    float* q     = (float*)d_ws;
    float* kk    = q  + (size_t)BB * NN * EMBED;
    float* vv    = kk + (size_t)BB * NN * EMBED;
    float* probs = vv + (size_t)BB * NN * EMBED;   // B*N*H*N floats = 33.5 MB

    ln1_qkv_kernel<<<BB * NN, 128, 0, stream>>>(x, ln1g, ln1b, Wq, bq, Wk, bk, Wv, bv, q, kk, vv);
    scores_softmax_kernel<<<BB * NN, 256, 0, stream>>>(pe, mask, q, kk, probs);
    pv_ffn_kernel<<<BB * NN / 4, 256, 0, stream>>>(x, probs, vv, Wo, bo,
                                                   ln2g, ln2b, W1, b1, W2, b2, out);
}

// Round 4
// 287.457 us; speedup vs baseline: 1.0419x; 1.0419x over previous
//
#include <hip/hip_runtime.h>
#include <hip/hip_bf16.h>

#define EMBED 128
#define HEADS 8
#define DH 16
#define FFN 512
#define BB 16
#define NN 256

// ---------------- Kernel A: LN1 + QKV projection (one block per row) -------
__global__ __launch_bounds__(128) void ln1_qkv_kernel(
    const float* __restrict__ x,
    const float* __restrict__ ln1_g, const float* __restrict__ ln1_b,
    const float* __restrict__ Wq, const float* __restrict__ bq,
    const float* __restrict__ Wk, const float* __restrict__ bk,
    const float* __restrict__ Wv, const float* __restrict__ bv,
    float* __restrict__ q, float* __restrict__ k, float* __restrict__ v)
{
    const int row = blockIdx.x;          // b*N + i
    const int e = threadIdx.x;           // 0..127
    __shared__ float red[128];
    __shared__ float xn[128];

    float xv = x[(size_t)row * EMBED + e];

    red[e] = xv;
    __syncthreads();
    for (int s = 64; s > 0; s >>= 1) { if (e < s) red[e] += red[e + s]; __syncthreads(); }
    float mu = red[0] * (1.0f / EMBED);
    __syncthreads();
    float d = xv - mu;
    red[e] = d * d;
    __syncthreads();
    for (int s = 64; s > 0; s >>= 1) { if (e < s) red[e] += red[e + s]; __syncthreads(); }
    float var = red[0] * (1.0f / EMBED);
    float rs = rsqrtf(var + 1e-5f);
    xn[e] = d * rs * ln1_g[e] + ln1_b[e];
    __syncthreads();

    float aq = bq[e], ak = bk[e], av = bv[e];
    #pragma unroll 8
    for (int c = 0; c < EMBED; ++c) {
        float xc = xn[c];
        aq += xc * Wq[c * EMBED + e];
        ak += xc * Wk[c * EMBED + e];
        av += xc * Wv[c * EMBED + e];
    }
    size_t o = (size_t)row * EMBED + e;
    q[o] = aq; k[o] = ak; v[o] = av;
}

// ---- Kernel A2: base = content*scale + mask (k is L2-resident) ------------
__global__ __launch_bounds__(256) void content_kernel(
    const float* __restrict__ mask,
    const float* __restrict__ q, const float* __restrict__ k,
    float* __restrict__ base)
{
    const int row = blockIdx.x;      // b*N + i
    const int bb  = row >> 8;
    const int t   = threadIdx.x;
    const int g   = t >> 5;          // group of 32 lanes; 8 groups
    const int l5  = t & 31;          // lane covers dims 4*l5..4*l5+3

    __shared__ float sc[HEADS][260];

    const float4 q4 = *reinterpret_cast<const float4*>(q + (size_t)row * EMBED + 4 * l5);
    const size_t k_base = (size_t)bb * NN * EMBED;
    const size_t mrow   = (size_t)row * NN;

    #pragma unroll 8
    for (int jt = 0; jt < 32; ++jt) {
        const int j = jt * 8 + g;
        const float4 k4 = *reinterpret_cast<const float4*>(k + k_base + (size_t)j * EMBED + 4 * l5);
        float s = q4.x * k4.x + q4.y * k4.y + q4.z * k4.z + q4.w * k4.w;
        s += __shfl_xor(s, 1);
        s += __shfl_xor(s, 2);
        if ((l5 & 3) == 0) sc[l5 >> 2][j] = s * 0.25f + mask[mrow + j];
    }
    __syncthreads();

    float* brow = base + (size_t)row * (HEADS * NN);
    #pragma unroll
    for (int p = 0; p < 8; ++p) brow[p * 256 + t] = sc[p][t];
}

// ---- Kernel B: pos scores (PURE pe stream) + softmax -> probs -------------
// Hot loop touches ONLY pe: 1 dwordx4 load + 4 FMA + 2 shuffles + ds_write.
__global__ __launch_bounds__(256) void pos_softmax_kernel(
    const float* __restrict__ pe,
    const float* __restrict__ q,
    const float* __restrict__ base,
    float* __restrict__ probs)
{
    const int row = blockIdx.x;      // b*N + i
    const int t   = threadIdx.x;
    const int g   = t >> 5;
    const int l5  = t & 31;

    __shared__ float sc[HEADS][260];    // pos partial scores
    __shared__ float bsc[HEADS][260];   // content*scale + mask (staged)

    const float4 q4 = *reinterpret_cast<const float4*>(q + (size_t)row * EMBED + 4 * l5);

    const float* brow = base + (size_t)row * (HEADS * NN);
    #pragma unroll
    for (int p = 0; p < 8; ++p) bsc[p][t] = brow[p * 256 + t];

    const size_t pe_base = (size_t)row * NN * EMBED;
    #pragma unroll 8
    for (int jt = 0; jt < 32; ++jt) {
        const int j = jt * 8 + g;
        const float4 p4 = *reinterpret_cast<const float4*>(pe + pe_base + (size_t)j * EMBED + 4 * l5);
        float s = q4.x * p4.x + q4.y * p4.y + q4.z * p4.z + q4.w * p4.w;
        s += __shfl_xor(s, 1);
        s += __shfl_xor(s, 2);
        if ((l5 & 3) == 0) sc[l5 >> 2][j] = s;
    }
    __syncthreads();

    // softmax per head; group g handles head g
    {
        float vals[8];
        float m = -1e30f;
        #pragma unroll
        for (int r = 0; r < 8; ++r) {
            vals[r] = fmaf(sc[g][l5 + 32 * r], 0.25f, bsc[g][l5 + 32 * r]);
            m = fmaxf(m, vals[r]);
        }
        #pragma unroll
        for (int off = 16; off >= 1; off >>= 1) m = fmaxf(m, __shfl_xor(m, off));
        float ssum = 0.f;
        #pragma unroll
        for (int r = 0; r < 8; ++r) { float e2 = __expf(vals[r] - m); vals[r] = e2; ssum += e2; }
        #pragma unroll
        for (int off = 16; off >= 1; off >>= 1) ssum += __shfl_xor(ssum, off);
        float inv = 1.0f / ssum;
        float* pout = probs + ((size_t)row * HEADS + g) * NN;
        #pragma unroll
        for (int r = 0; r < 8; ++r) pout[l5 + 32 * r] = vals[r] * inv;
    }
}

// ---- Kernel C: PV + Wo + residual + LN2 + FFN + residual ------------------
// One block per 4 rows of the same batch: weights/v read once, used 4x.
__global__ __launch_bounds__(256) void pv_ffn_kernel(
    const float* __restrict__ x,
    const float* __restrict__ probs,
    const float* __restrict__ v,
    const float* __restrict__ Wo, const float* __restrict__ bo,
    const float* __restrict__ ln2_g, const float* __restrict__ ln2_b,
    const float* __restrict__ W1, const float* __restrict__ b1,
    const float* __restrict__ W2, const float* __restrict__ b2,
    float* __restrict__ out)
{
    const int blk  = blockIdx.x;         // 0..1023
    const int b    = blk >> 6;           // 64 blocks per batch
    const int row0 = b * NN + ((blk & 63) << 2);   // first of 4 global rows
    const int t    = threadIdx.x;        // 0..255

    __shared__ float pr[4][HEADS][NN + 1];
    __shared__ float pvred[2][4][EMBED];
    __shared__ float ctx[4][EMBED];
    __shared__ float x2s[4][EMBED];
    __shared__ float xn2[4][EMBED];
    __shared__ float hb[4][FFN];
    __shared__ float mus[4], rss[4];

    #pragma unroll
    for (int rh = 0; rh < 32; ++rh) {
        const int r = rh >> 3, h = rh & 7;
        pr[r][h][t] = probs[((size_t)(row0 + r) * HEADS + h) * NN + t];
    }
    __syncthreads();

    {
        const int e = t & 127, half = t >> 7, h = e >> 4;
        float a0 = 0.f, a1 = 0.f, a2 = 0.f, a3 = 0.f;
        const float* vb = v + ((size_t)(b * NN + half * 128)) * EMBED + e;
        const float* p0 = &pr[0][h][half * 128];
        const float* p1 = &pr[1][h][half * 128];
        const float* p2 = &pr[2][h][half * 128];
        const float* p3 = &pr[3][h][half * 128];
        #pragma unroll 8
        for (int j = 0; j < 128; ++j) {
            const float vv = vb[(size_t)j * EMBED];
            a0 += p0[j] * vv; a1 += p1[j] * vv; a2 += p2[j] * vv; a3 += p3[j] * vv;
        }
        pvred[half][0][e] = a0; pvred[half][1][e] = a1;
        pvred[half][2][e] = a2; pvred[half][3][e] = a3;
    }
    __syncthreads();
    if (t < 128) {
        #pragma unroll
        for (int r = 0; r < 4; ++r) ctx[r][t] = pvred[0][r][t] + pvred[1][r][t];
    }
    __syncthreads();

    {
        const int e = t & 127, rp = t >> 7;
        float a0 = bo[e], a1 = bo[e];
        #pragma unroll 8
        for (int c = 0; c < EMBED; ++c) {
            const float w = Wo[c * EMBED + e];
            a0 += ctx[2 * rp][c] * w;
            a1 += ctx[2 * rp + 1][c] * w;
        }
        a0 += x[(size_t)(row0 + 2 * rp) * EMBED + e];
        a1 += x[(size_t)(row0 + 2 * rp + 1) * EMBED + e];
        x2s[2 * rp][e] = a0;
        x2s[2 * rp + 1][e] = a1;
    }
    __syncthreads();

    {
        const int wid = t >> 6, l64 = t & 63;
        if (wid < 4) {
            const float v0 = x2s[wid][l64], v1 = x2s[wid][l64 + 64];
            float s = v0 + v1;
            float sq = v0 * v0 + v1 * v1;
            #pragma unroll
            for (int off = 32; off >= 1; off >>= 1) {
                s  += __shfl_xor(s, off);
                sq += __shfl_xor(sq, off);
            }
            if (l64 == 0) {
                const float mu = s * (1.0f / EMBED);
                const float var = sq * (1.0f / EMBED) - mu * mu;
                mus[wid] = mu;
                rss[wid] = rsqrtf(var + 1e-5f);
            }
        }
    }
    __syncthreads();
    {
        #pragma unroll
        for (int rr = 0; rr < 2; ++rr) {
            const int flat = t + 256 * rr;
            const int r = flat >> 7, e = flat & 127;
            xn2[r][e] = (x2s[r][e] - mus[r]) * rss[r] * ln2_g[e] + ln2_b[e];
        }
    }
    __syncthreads();

    {
        float h0[4], h1[4];
        #pragma unroll
        for (int r = 0; r < 4; ++r) { h0[r] = b1[t]; h1[r] = b1[t + 256]; }
        #pragma unroll 4
        for (int c = 0; c < EMBED; ++c) {
            const float w0 = W1[c * FFN + t];
            const float w1 = W1[c * FFN + t + 256];
            #pragma unroll
            for (int r = 0; r < 4; ++r) {
                const float xc = xn2[r][c];
                h0[r] += xc * w0;
                h1[r] += xc * w1;
            }
        }
        #pragma unroll
        for (int r = 0; r < 4; ++r) {
            hb[r][t]       = fmaxf(h0[r], 0.f);
            hb[r][t + 256] = fmaxf(h1[r], 0.f);
        }
    }
    __syncthreads();

    {
        const int e = t & 127, rp = t >> 7;
        const int ra = 2 * rp, rb = 2 * rp + 1;
        float a0 = b2[e], a1 = b2[e];
        #pragma unroll 8
        for (int f = 0; f < FFN; ++f) {
            const float w = W2[f * EMBED + e];
            a0 += hb[ra][f] * w;
            a1 += hb[rb][f] * w;
        }
        out[(size_t)(row0 + ra) * EMBED + e] = x2s[ra][e] + a0;
        out[(size_t)(row0 + rb) * EMBED + e] = x2s[rb][e] + a1;
    }
}

extern "C" void kernel_launch(void* const* d_in, const int* in_sizes, int n_in,
                              void* d_out, int out_size, void* d_ws, size_t ws_size,
                              hipStream_t stream) {
    const float* x    = (const float*)d_in[0];
    const float* pe   = (const float*)d_in[1];
    const float* mask = (const float*)d_in[2];
    const float* ln1g = (const float*)d_in[3];
    const float* ln1b = (const float*)d_in[4];
    const float* Wq   = (const float*)d_in[5];
    const float* bq   = (const float*)d_in[6];
    const float* Wk   = (const float*)d_in[7];
    const float* bk   = (const float*)d_in[8];
    const float* Wv   = (const float*)d_in[9];
    const float* bv   = (const float*)d_in[10];
    const float* Wo   = (const float*)d_in[11];
    const float* bo   = (const float*)d_in[12];
    const float* ln2g = (const float*)d_in[13];
    const float* ln2b = (const float*)d_in[14];
    const float* W1   = (const float*)d_in[15];
    const float* b1   = (const float*)d_in[16];
    const float* W2   = (const float*)d_in[17];
    const float* b2   = (const float*)d_in[18];
    float* out = (float*)d_out;

    float* q     = (float*)d_ws;
    float* kk    = q     + (size_t)BB * NN * EMBED;
    float* vv    = kk    + (size_t)BB * NN * EMBED;
    float* probs = vv    + (size_t)BB * NN * EMBED;   // 33.5 MB
    float* base  = probs + (size_t)BB * NN * HEADS * NN;  // 33.5 MB

    ln1_qkv_kernel<<<BB * NN, 128, 0, stream>>>(x, ln1g, ln1b, Wq, bq, Wk, bk, Wv, bv, q, kk, vv);
    content_kernel<<<BB * NN, 256, 0, stream>>>(mask, q, kk, base);
    pos_softmax_kernel<<<BB * NN, 256, 0, stream>>>(pe, q, base, probs);
    pv_ffn_kernel<<<BB * NN / 4, 256, 0, stream>>>(x, probs, vv, Wo, bo,
                                                   ln2g, ln2b, W1, b1, W2, b2, out);
}

// Round 5
// 225.671 us; speedup vs baseline: 1.3272x; 1.2738x over previous
//
#include <hip/hip_runtime.h>
#include <hip/hip_bf16.h>

#define EMBED 128
#define HEADS 8
#define DH 16
#define FFN 512
#define BB 16
#define NN 256

// ---------------- Kernel A: LN1 + QKV projection (one block per row) -------
__global__ __launch_bounds__(128) void ln1_qkv_kernel(
    const float* __restrict__ x,
    const float* __restrict__ ln1_g, const float* __restrict__ ln1_b,
    const float* __restrict__ Wq, const float* __restrict__ bq,
    const float* __restrict__ Wk, const float* __restrict__ bk,
    const float* __restrict__ Wv, const float* __restrict__ bv,
    float* __restrict__ q, float* __restrict__ k, float* __restrict__ v)
{
    const int row = blockIdx.x;          // b*N + i
    const int e = threadIdx.x;           // 0..127
    __shared__ float red[128];
    __shared__ float xn[128];

    float xv = x[(size_t)row * EMBED + e];

    red[e] = xv;
    __syncthreads();
    for (int s = 64; s > 0; s >>= 1) { if (e < s) red[e] += red[e + s]; __syncthreads(); }
    float mu = red[0] * (1.0f / EMBED);
    __syncthreads();
    float d = xv - mu;
    red[e] = d * d;
    __syncthreads();
    for (int s = 64; s > 0; s >>= 1) { if (e < s) red[e] += red[e + s]; __syncthreads(); }
    float var = red[0] * (1.0f / EMBED);
    float rs = rsqrtf(var + 1e-5f);
    xn[e] = d * rs * ln1_g[e] + ln1_b[e];
    __syncthreads();

    float aq = bq[e], ak = bk[e], av = bv[e];
    #pragma unroll 8
    for (int c = 0; c < EMBED; ++c) {
        float xc = xn[c];
        aq += xc * Wq[c * EMBED + e];
        ak += xc * Wk[c * EMBED + e];
        av += xc * Wv[c * EMBED + e];
    }
    size_t o = (size_t)row * EMBED + e;
    q[o] = aq; k[o] = ak; v[o] = av;
}

// ---- Kernel B: scores (content + pos) + softmax -> probs ------------------
// One block per (b,i) row. Hot loop: 2 dwordx4 loads + 32 VALU + 2 shfl +
// masked ds_write. Mask folded in at softmax time (staged in LDS).
__global__ __launch_bounds__(256) void scores_softmax_kernel(
    const float* __restrict__ pe,
    const float* __restrict__ mask,
    const float* __restrict__ q, const float* __restrict__ k,
    float* __restrict__ probs)
{
    const int row = blockIdx.x;      // b*N + i
    const int bb  = row >> 8;        // N = 256
    const int t   = threadIdx.x;     // 0..255

    __shared__ float sc[HEADS][260];
    __shared__ float qs[EMBED];
    __shared__ float msk[NN];

    if (t < EMBED) qs[t] = q[(size_t)row * EMBED + t];
    msk[t] = mask[(size_t)row * NN + t];
    __syncthreads();

    const int g = t >> 5;            // 0..7 (group of 32 lanes)
    const int l = t & 31;            // lane covers dims 4l..4l+3
    float4 q4 = *reinterpret_cast<const float4*>(&qs[4 * l]);

    const size_t pe_row = (size_t)row * NN * EMBED;
    #pragma unroll 4
    for (int jt = 0; jt < 32; ++jt) {
        const int j = jt * 8 + g;
        const float4 p4 = *reinterpret_cast<const float4*>(pe + pe_row + (size_t)j * EMBED + 4 * l);
        const float4 k4 = *reinterpret_cast<const float4*>(k + (size_t)(bb * NN + j) * EMBED + 4 * l);
        float s = q4.x * (k4.x + p4.x) + q4.y * (k4.y + p4.y)
                + q4.z * (k4.z + p4.z) + q4.w * (k4.w + p4.w);
        s += __shfl_xor(s, 1);
        s += __shfl_xor(s, 2);
        if ((l & 3) == 0) {
            sc[l >> 2][j] = s * 0.25f;     // 1/sqrt(16)
        }
    }
    __syncthreads();

    // softmax per head; group g handles head g; write probs [row][h][j]
    {
        float vals[8];
        float m = -1e30f;
        #pragma unroll
        for (int r = 0; r < 8; ++r) {
            vals[r] = sc[g][l + 32 * r] + msk[l + 32 * r];
            m = fmaxf(m, vals[r]);
        }
        #pragma unroll
        for (int off = 16; off >= 1; off >>= 1) m = fmaxf(m, __shfl_xor(m, off));
        float ssum = 0.f;
        #pragma unroll
        for (int r = 0; r < 8; ++r) { float e2 = __expf(vals[r] - m); vals[r] = e2; ssum += e2; }
        #pragma unroll
        for (int off = 16; off >= 1; off >>= 1) ssum += __shfl_xor(ssum, off);
        float inv = 1.0f / ssum;
        float* pout = probs + ((size_t)row * HEADS + g) * NN;
        #pragma unroll
        for (int r = 0; r < 8; ++r) pout[l + 32 * r] = vals[r] * inv;
    }
}

// ---- Kernel C: PV + Wo + residual + LN2 + FFN + residual ------------------
// One block per 4 rows. Vectorized float4 loads throughout; ~22 KB LDS for
// high occupancy; probs read from L2 (4-lane broadcast) instead of staging.
__global__ __launch_bounds__(256) void pv_ffn_kernel(
    const float* __restrict__ x,
    const float* __restrict__ probs,
    const float* __restrict__ v,
    const float* __restrict__ Wo, const float* __restrict__ bo,
    const float* __restrict__ ln2_g, const float* __restrict__ ln2_b,
    const float* __restrict__ W1, const float* __restrict__ b1,
    const float* __restrict__ W2, const float* __restrict__ b2,
    float* __restrict__ out)
{
    const int blk  = blockIdx.x;         // 0..1023
    const int b    = blk >> 6;
    const int row0 = b * NN + ((blk & 63) << 2);
    const int t    = threadIdx.x;        // 0..255

    __shared__ float ctx[4][EMBED];          // 2 KB
    __shared__ float x2s[4][EMBED];          // 2 KB
    __shared__ float xn2[4][EMBED];          // 2 KB
    __shared__ float hb[4][FFN];             // 8 KB
    __shared__ float red4[4][4][EMBED];      // 8 KB generic reduction buffer
    __shared__ float mus[4], rss[4];

    const int e4  = t & 31;       // float4 column: e = 4*e4..4*e4+3
    const int grp = t >> 5;       // 0..7

    // ---- PV: ctx[r][e] = sum_j probs[row0+r][h(e)][j] * v[b][j][e] --------
    {
        const int seg = grp;             // j in [32*seg, 32*seg+32)
        const int h   = e4 >> 2;
        float4 a0 = {0,0,0,0}, a1 = a0, a2 = a0, a3 = a0;
        const float* vb = v + ((size_t)(b * NN + seg * 32)) * EMBED + 4 * e4;
        const size_t p0o = ((size_t)(row0 + 0) * HEADS + h) * NN + seg * 32;
        const size_t p1o = ((size_t)(row0 + 1) * HEADS + h) * NN + seg * 32;
        const size_t p2o = ((size_t)(row0 + 2) * HEADS + h) * NN + seg * 32;
        const size_t p3o = ((size_t)(row0 + 3) * HEADS + h) * NN + seg * 32;
        #pragma unroll 4
        for (int jj = 0; jj < 32; ++jj) {
            const float4 v4 = *reinterpret_cast<const float4*>(vb + (size_t)jj * EMBED);
            const float p0 = probs[p0o + jj];
            const float p1 = probs[p1o + jj];
            const float p2 = probs[p2o + jj];
            const float p3 = probs[p3o + jj];
            a0.x += p0*v4.x; a0.y += p0*v4.y; a0.z += p0*v4.z; a0.w += p0*v4.w;
            a1.x += p1*v4.x; a1.y += p1*v4.y; a1.z += p1*v4.z; a1.w += p1*v4.w;
            a2.x += p2*v4.x; a2.y += p2*v4.y; a2.z += p2*v4.z; a2.w += p2*v4.w;
            a3.x += p3*v4.x; a3.y += p3*v4.y; a3.z += p3*v4.z; a3.w += p3*v4.w;
        }
        // combine seg pairs (t ^ 32 has same e4, adjacent seg)
        a0.x += __shfl_xor(a0.x, 32); a0.y += __shfl_xor(a0.y, 32);
        a0.z += __shfl_xor(a0.z, 32); a0.w += __shfl_xor(a0.w, 32);
        a1.x += __shfl_xor(a1.x, 32); a1.y += __shfl_xor(a1.y, 32);
        a1.z += __shfl_xor(a1.z, 32); a1.w += __shfl_xor(a1.w, 32);
        a2.x += __shfl_xor(a2.x, 32); a2.y += __shfl_xor(a2.y, 32);
        a2.z += __shfl_xor(a2.z, 32); a2.w += __shfl_xor(a2.w, 32);
        a3.x += __shfl_xor(a3.x, 32); a3.y += __shfl_xor(a3.y, 32);
        a3.z += __shfl_xor(a3.z, 32); a3.w += __shfl_xor(a3.w, 32);
        if ((t & 63) < 32) {
            const int w = t >> 6;
            *reinterpret_cast<float4*>(&red4[w][0][4 * e4]) = a0;
            *reinterpret_cast<float4*>(&red4[w][1][4 * e4]) = a1;
            *reinterpret_cast<float4*>(&red4[w][2][4 * e4]) = a2;
            *reinterpret_cast<float4*>(&red4[w][3][4 * e4]) = a3;
        }
    }
    __syncthreads();
    if (t < 128) {
        #pragma unroll
        for (int r = 0; r < 4; ++r)
            ctx[r][t] = red4[0][r][t] + red4[1][r][t] + red4[2][r][t] + red4[3][r][t];
    }
    __syncthreads();

    // ---- Wo: grp -> (r = grp&3, ch = grp>>2 covers half the c-range) ------
    {
        const int r = grp & 3, ch = grp >> 2;
        float4 wacc = {0,0,0,0};
        const float* Wob = Wo + ch * 64 * EMBED + 4 * e4;
        #pragma unroll 8
        for (int cc = 0; cc < 64; ++cc) {
            const float4 w4 = *reinterpret_cast<const float4*>(Wob + (size_t)cc * EMBED);
            const float xc = ctx[r][ch * 64 + cc];
            wacc.x += xc*w4.x; wacc.y += xc*w4.y; wacc.z += xc*w4.z; wacc.w += xc*w4.w;
        }
        *reinterpret_cast<float4*>(&red4[ch][r][4 * e4]) = wacc;
    }
    __syncthreads();
    {
        #pragma unroll
        for (int rr = 0; rr < 2; ++rr) {
            const int idx = t + 256 * rr;          // 0..511
            const int r = idx >> 7, e = idx & 127;
            x2s[r][e] = red4[0][r][e] + red4[1][r][e] + bo[e]
                      + x[(size_t)(row0 + r) * EMBED + e];
        }
    }
    __syncthreads();

    // ---- LN2: wave w reduces row w ---------------------------------------
    {
        const int wid = t >> 6, l64 = t & 63;
        const float v0 = x2s[wid][l64], v1 = x2s[wid][l64 + 64];
        float s = v0 + v1;
        float sq = v0 * v0 + v1 * v1;
        #pragma unroll
        for (int off = 32; off >= 1; off >>= 1) {
            s  += __shfl_xor(s, off);
            sq += __shfl_xor(sq, off);
        }
        if (l64 == 0) {
            const float mu = s * (1.0f / EMBED);
            const float var = sq * (1.0f / EMBED) - mu * mu;
            mus[wid] = mu;
            rss[wid] = rsqrtf(var + 1e-5f);
        }
    }
    __syncthreads();
    {
        #pragma unroll
        for (int rr = 0; rr < 2; ++rr) {
            const int idx = t + 256 * rr;
            const int r = idx >> 7, e = idx & 127;
            xn2[r][e] = (x2s[r][e] - mus[r]) * rss[r] * ln2_g[e] + ln2_b[e];
        }
    }
    __syncthreads();

    // ---- FFN1: t -> (f4 = t&127 float4 hidden col, rh = t>>7 row pair) ----
    {
        const int f4 = t & 127, rh = t >> 7;
        const int r0 = 2 * rh, r1 = r0 + 1;
        float4 h0 = *reinterpret_cast<const float4*>(&b1[4 * f4]);
        float4 h1 = h0;
        const float* W1b = W1 + 4 * f4;
        #pragma unroll 8
        for (int c = 0; c < 128; ++c) {
            const float4 w4 = *reinterpret_cast<const float4*>(W1b + (size_t)c * FFN);
            const float xa = xn2[r0][c], xb = xn2[r1][c];
            h0.x += xa*w4.x; h0.y += xa*w4.y; h0.z += xa*w4.z; h0.w += xa*w4.w;
            h1.x += xb*w4.x; h1.y += xb*w4.y; h1.z += xb*w4.z; h1.w += xb*w4.w;
        }
        h0.x = fmaxf(h0.x, 0.f); h0.y = fmaxf(h0.y, 0.f);
        h0.z = fmaxf(h0.z, 0.f); h0.w = fmaxf(h0.w, 0.f);
        h1.x = fmaxf(h1.x, 0.f); h1.y = fmaxf(h1.y, 0.f);
        h1.z = fmaxf(h1.z, 0.f); h1.w = fmaxf(h1.w, 0.f);
        *reinterpret_cast<float4*>(&hb[r0][4 * f4]) = h0;
        *reinterpret_cast<float4*>(&hb[r1][4 * f4]) = h1;
    }
    __syncthreads();

    // ---- FFN2: grp -> (r = grp&3, fq = grp>>2 covers half the f-range) ----
    {
        const int r = grp & 3, fq = grp >> 2;
        float4 facc = {0,0,0,0};
        const float* W2b = W2 + (size_t)fq * 256 * EMBED + 4 * e4;
        #pragma unroll 8
        for (int ff = 0; ff < 256; ++ff) {
            const float4 w4 = *reinterpret_cast<const float4*>(W2b + (size_t)ff * EMBED);
            const float hv = hb[r][fq * 256 + ff];
            facc.x += hv*w4.x; facc.y += hv*w4.y; facc.z += hv*w4.z; facc.w += hv*w4.w;
        }
        *reinterpret_cast<float4*>(&red4[fq][r][4 * e4]) = facc;
    }
    __syncthreads();
    {
        #pragma unroll
        for (int rr = 0; rr < 2; ++rr) {
            const int idx = t + 256 * rr;
            const int r = idx >> 7, e = idx & 127;
            out[(size_t)(row0 + r) * EMBED + e] =
                x2s[r][e] + b2[e] + red4[0][r][e] + red4[1][r][e];
        }
    }
}

extern "C" void kernel_launch(void* const* d_in, const int* in_sizes, int n_in,
                              void* d_out, int out_size, void* d_ws, size_t ws_size,
                              hipStream_t stream) {
    const float* x    = (const float*)d_in[0];
    const float* pe   = (const float*)d_in[1];
    const float* mask = (const float*)d_in[2];
    const float* ln1g = (const float*)d_in[3];
    const float* ln1b = (const float*)d_in[4];
    const float* Wq   = (const float*)d_in[5];
    const float* bq   = (const float*)d_in[6];
    const float* Wk   = (const float*)d_in[7];
    const float* bk   = (const float*)d_in[8];
    const float* Wv   = (const float*)d_in[9];
    const float* bv   = (const float*)d_in[10];
    const float* Wo   = (const float*)d_in[11];
    const float* bo   = (const float*)d_in[12];
    const float* ln2g = (const float*)d_in[13];
    const float* ln2b = (const float*)d_in[14];
    const float* W1   = (const float*)d_in[15];
    const float* b1   = (const float*)d_in[16];
    const float* W2   = (const float*)d_in[17];
    const float* b2   = (const float*)d_in[18];
    float* out = (float*)d_out;

    float* q     = (float*)d_ws;
    float* kk    = q  + (size_t)BB * NN * EMBED;
    float* vv    = kk + (size_t)BB * NN * EMBED;
    float* probs = vv + (size_t)BB * NN * EMBED;   // 33.5 MB

    ln1_qkv_kernel<<<BB * NN, 128, 0, stream>>>(x, ln1g, ln1b, Wq, bq, Wk, bk, Wv, bv, q, kk, vv);
    scores_softmax_kernel<<<BB * NN, 256, 0, stream>>>(pe, mask, q, kk, probs);
    pv_ffn_kernel<<<BB * NN / 4, 256, 0, stream>>>(x, probs, vv, Wo, bo,
                                                   ln2g, ln2b, W1, b1, W2, b2, out);
}